// Round 1
// baseline (242.606 us; speedup 1.0000x reference)
//
#include <hip/hip_runtime.h>
#include <math.h>

#define B_ 2
#define N_ 4100
#define C_ 768
#define T_ 4
#define H_ 12
#define D_ 64
#define M_ 4096
#define S_ 48          // T_*H_
#define SCALE 0.125f   // d^-0.5 = 1/8

// ---- top-2 helpers (ties -> lowest index, matching jax.lax.top_k) ----
__device__ __forceinline__ bool better(float va, int ia, float vb, int ib) {
  return (va > vb) || (va == vb && ia < ib);
}

// merge candidate pair (ov1,oi1,ov2,oi2) into (v1,i1,v2,i2); both sorted desc
__device__ __forceinline__ void merge2(float& v1, int& i1, float& v2, int& i2,
                                       float ov1, int oi1, float ov2, int oi2) {
  if (better(ov1, oi1, v1, i1)) {
    float tv; int ti;
    tv = v1; ti = i1; v1 = ov1; i1 = oi1; ov1 = tv; oi1 = ti;
    tv = v2; ti = i2; v2 = ov2; i2 = oi2; ov2 = tv; oi2 = ti;
  }
  if (better(ov1, oi1, v2, i2)) { v2 = ov1; i2 = oi1; }
}

// ---- K1: qk[b,t,h,c] = SCALE * sum_j (x[b,t,:]·qs_w[t,h*64+j,:]) * kv_w[h*64+j,c]
__global__ __launch_bounds__(256) void qk_kernel(const float* __restrict__ x,
    const float* __restrict__ qs_w, const float* __restrict__ kv_w,
    float* __restrict__ qk) {
  const int blk = blockIdx.x;            // b*T_*H_ + t*H_ + h
  const int h = blk % H_;
  const int t = (blk / H_) % T_;
  const int b = blk / (T_ * H_);
  const int tid = threadIdx.x;
  __shared__ float xs[C_];
  __shared__ float partial[256];
  __shared__ float qseg[D_];
  for (int i = tid; i < C_; i += 256) xs[i] = x[((size_t)b * N_ + t) * C_ + i];
  __syncthreads();
  {
    const int j = tid & 63;
    const int part = tid >> 6;           // 4 parts of 192 channels
    const float* wrow = qs_w + ((size_t)t * C_ + h * D_ + j) * C_;
    float a = 0.f;
    for (int c = part * 192; c < part * 192 + 192; ++c) a += xs[c] * wrow[c];
    partial[tid] = a;
  }
  __syncthreads();
  if (tid < 64)
    qseg[tid] = (partial[tid] + partial[tid + 64] + partial[tid + 128] + partial[tid + 192]) * SCALE;
  __syncthreads();
  for (int c = tid; c < C_; c += 256) {
    float a = 0.f;
    #pragma unroll 8
    for (int j = 0; j < 64; ++j) a += qseg[j] * kv_w[((size_t)(h * D_ + j)) * C_ + c];
    qk[(((size_t)b * T_ + t) * H_ + h) * C_ + c] = a;
  }
}

// ---- K2: scores + per-64-m-tile top-2 candidates; also zeroes feature-output rows
__global__ __launch_bounds__(256) void score_kernel(const float* __restrict__ x,
    const float* __restrict__ qk, float* __restrict__ out, float* __restrict__ cand) {
  const int b = blockIdx.x >> 6;
  const int mt = blockIdx.x & 63;        // 64 tiles of 64 m
  const int tid = threadIdx.x;
  const int m0 = mt * 64;

  __shared__ __align__(16) float fbuf[64][68];   // 64 m x 64 c, padded
  __shared__ __align__(16) float qkbuf[48][68];  // 48 s x 64 c, padded

  // zero output rows (b, T_+m0 .. T_+m0+63) — harness poisons d_out with 0xAA
  {
    float4 z = make_float4(0.f, 0.f, 0.f, 0.f);
    float4* outv = (float4*)(out + ((size_t)b * N_ + T_ + m0) * C_);
    for (int i = tid; i < 64 * C_ / 4; i += 256) outv[i] = z;
  }

  const int mg = tid & 15;   // 16 m-groups: m_local = mg + 16*u
  const int sg = tid >> 4;   // 16 s-groups of 3: s = sg*3 + i

  float acc[4][3];
  #pragma unroll
  for (int u = 0; u < 4; ++u)
    #pragma unroll
    for (int i = 0; i < 3; ++i) acc[u][i] = 0.f;

  const float* xb = x + ((size_t)b * N_ + T_ + m0) * C_;
  const float* qkb = qk + (size_t)b * S_ * C_;

  for (int cc = 0; cc < 12; ++cc) {
    __syncthreads();
    for (int i = tid; i < 64 * 16; i += 256) {
      int row = i >> 4, c4 = i & 15;
      *(float4*)&fbuf[row][c4 * 4] =
          *(const float4*)(xb + (size_t)row * C_ + cc * 64 + c4 * 4);
    }
    for (int i = tid; i < 48 * 16; i += 256) {
      int s = i >> 4, c4 = i & 15;
      *(float4*)&qkbuf[s][c4 * 4] =
          *(const float4*)(qkb + (size_t)s * C_ + cc * 64 + c4 * 4);
    }
    __syncthreads();
    #pragma unroll 4
    for (int c4 = 0; c4 < 16; ++c4) {
      float4 f[4], q[3];
      f[0] = *(const float4*)&fbuf[mg][c4 * 4];
      f[1] = *(const float4*)&fbuf[mg + 16][c4 * 4];
      f[2] = *(const float4*)&fbuf[mg + 32][c4 * 4];
      f[3] = *(const float4*)&fbuf[mg + 48][c4 * 4];
      q[0] = *(const float4*)&qkbuf[sg * 3 + 0][c4 * 4];
      q[1] = *(const float4*)&qkbuf[sg * 3 + 1][c4 * 4];
      q[2] = *(const float4*)&qkbuf[sg * 3 + 2][c4 * 4];
      #pragma unroll
      for (int u = 0; u < 4; ++u)
        #pragma unroll
        for (int i = 0; i < 3; ++i)
          acc[u][i] += f[u].x * q[i].x + f[u].y * q[i].y +
                       f[u].z * q[i].z + f[u].w * q[i].w;
    }
  }

  // per-s top-2: local over 4 m, then butterfly across the 16-lane mg group
  for (int i = 0; i < 3; ++i) {
    float v1 = -INFINITY, v2 = -INFINITY;
    int i1 = 0x7fffffff, i2 = 0x7fffffff;
    #pragma unroll
    for (int u = 0; u < 4; ++u) {
      float v = acc[u][i];
      int m = m0 + mg + 16 * u;
      if (better(v, m, v1, i1)) { v2 = v1; i2 = i1; v1 = v; i1 = m; }
      else if (better(v, m, v2, i2)) { v2 = v; i2 = m; }
    }
    #pragma unroll
    for (int off = 1; off < 16; off <<= 1) {
      float ov1 = __shfl_xor(v1, off);
      int   oi1 = __shfl_xor(i1, off);
      float ov2 = __shfl_xor(v2, off);
      int   oi2 = __shfl_xor(i2, off);
      merge2(v1, i1, v2, i2, ov1, oi1, ov2, oi2);
    }
    if (mg == 0) {
      int s = sg * 3 + i;
      float* cp = cand + (((size_t)b * S_ + s) * 64 + mt) * 4;
      cp[0] = v1; ((int*)cp)[1] = i1; cp[2] = v2; ((int*)cp)[3] = i2;
    }
  }
}

// ---- K3: merge 64 tile candidates -> global top-2 + softmax weights
__global__ __launch_bounds__(64) void merge_kernel(const float* __restrict__ cand,
                                                   float* __restrict__ top2) {
  const int blk = blockIdx.x;   // b*S_ + s
  const int lane = threadIdx.x; // 64 lanes = 64 tiles
  const float* cp = cand + ((size_t)blk * 64 + lane) * 4;
  float v1 = cp[0]; int i1 = ((const int*)cp)[1];
  float v2 = cp[2]; int i2 = ((const int*)cp)[3];
  #pragma unroll
  for (int off = 1; off < 64; off <<= 1) {
    float ov1 = __shfl_xor(v1, off);
    int   oi1 = __shfl_xor(i1, off);
    float ov2 = __shfl_xor(v2, off);
    int   oi2 = __shfl_xor(i2, off);
    merge2(v1, i1, v2, i2, ov1, oi1, ov2, oi2);
  }
  if (lane == 0) {
    float w1 = 1.f / (1.f + expf(v2 - v1));   // softmax over [v1, v2], v1 >= v2
    float* tp = top2 + (size_t)blk * 4;
    ((int*)tp)[0] = i1; ((int*)tp)[1] = i2;
    tp[2] = w1; tp[3] = 1.f - w1;
  }
}

// ---- K4: v-projection at selected tokens -> attn_token; sparse feature_output scatter
__global__ __launch_bounds__(64) void gather_kernel(const float* __restrict__ x,
    const float* __restrict__ kv_w, const float* __restrict__ experts_w,
    const float* __restrict__ top2, float* __restrict__ attn, float* __restrict__ out) {
  const int blk = blockIdx.x;   // b*S_ + s ; s = t*H_ + h
  const int h = blk % H_;
  const int t = (blk / H_) % T_;
  const int b = blk / S_;
  const int lane = threadIdx.x;
  const float* tp = top2 + (size_t)blk * 4;
  const int i1 = ((const int*)tp)[0];
  const int i2 = ((const int*)tp)[1];
  const float w1 = tp[2], w2 = tp[3];
  __shared__ float frow[2][C_];
  for (int i = lane; i < C_; i += 64) {
    frow[0][i] = x[((size_t)b * N_ + T_ + i1) * C_ + i];
    frow[1][i] = x[((size_t)b * N_ + T_ + i2) * C_ + i];
  }
  __syncthreads();
  {  // v[b,h,m,j] for j = lane; attn_token = w1*v(i1) + w2*v(i2)
    const float* kr = kv_w + ((size_t)(C_ + h * D_ + lane)) * C_;
    float a0 = 0.f, a1 = 0.f;
    for (int c = 0; c < C_; ++c) {
      float kv = kr[c];
      a0 += frow[0][c] * kv;
      a1 += frow[1][c] * kv;
    }
    attn[((size_t)b * T_ + t) * C_ + h * D_ + lane] = w1 * a0 + w2 * a1;
  }
  // feature_output[b, m_k, o] += w_k * (experts_w[t][o, hblk]·feature[b, m_k, hblk])
  const size_t r0 = ((size_t)b * N_ + T_ + i1) * C_;
  const size_t r1 = ((size_t)b * N_ + T_ + i2) * C_;
  for (int o = lane; o < C_; o += 64) {
    const float* er = experts_w + ((size_t)t * C_ + o) * C_ + h * D_;
    float a0 = 0.f, a1 = 0.f;
    #pragma unroll 8
    for (int c = 0; c < D_; ++c) {
      float e = er[c];
      a0 += e * frow[0][h * D_ + c];
      a1 += e * frow[1][h * D_ + c];
    }
    atomicAdd(&out[r0 + o], w1 * a0);
    atomicAdd(&out[r1 + o], w2 * a1);
  }
}

// ---- K5: token_output[b,t,o] = attn_token[b,t,:]·experts_w[t,o,:]
__global__ __launch_bounds__(64) void token_kernel(const float* __restrict__ attn,
    const float* __restrict__ experts_w, float* __restrict__ out) {
  const int blk = blockIdx.x;   // (b*T_+t)*12 + oc
  const int oc = blk % 12;
  const int t = (blk / 12) % T_;
  const int b = blk / (12 * T_);
  const int lane = threadIdx.x;
  __shared__ float arow[C_];
  for (int i = lane; i < C_; i += 64) arow[i] = attn[((size_t)b * T_ + t) * C_ + i];
  __syncthreads();
  const int o = oc * 64 + lane;
  const float* er = experts_w + ((size_t)t * C_ + o) * C_;
  float a = 0.f;
  for (int c = 0; c < C_; ++c) a += arow[c] * er[c];
  out[((size_t)b * N_ + t) * C_ + o] = a;
}

extern "C" void kernel_launch(void* const* d_in, const int* in_sizes, int n_in,
                              void* d_out, int out_size, void* d_ws, size_t ws_size,
                              hipStream_t stream) {
  const float* x         = (const float*)d_in[0];
  const float* qs_w      = (const float*)d_in[1];
  const float* kv_w      = (const float*)d_in[2];
  const float* experts_w = (const float*)d_in[3];
  float* out = (float*)d_out;

  float* ws   = (float*)d_ws;
  float* qk   = ws;                                  // B*S*C      = 73728 floats
  float* cand = qk + (size_t)B_ * S_ * C_;           // B*S*64*4   = 24576
  float* top2 = cand + (size_t)B_ * S_ * 64 * 4;     // B*S*4      = 384
  float* attn = top2 + (size_t)B_ * S_ * 4;          // B*T*C      = 6144

  hipLaunchKernelGGL(qk_kernel,    dim3(B_ * T_ * H_), dim3(256), 0, stream, x, qs_w, kv_w, qk);
  hipLaunchKernelGGL(score_kernel, dim3(B_ * 64),      dim3(256), 0, stream, x, qk, out, cand);
  hipLaunchKernelGGL(merge_kernel, dim3(B_ * S_),      dim3(64),  0, stream, cand, top2);
  hipLaunchKernelGGL(gather_kernel,dim3(B_ * S_),      dim3(64),  0, stream, x, kv_w, experts_w, top2, attn, out);
  hipLaunchKernelGGL(token_kernel, dim3(B_ * T_ * 12), dim3(64),  0, stream, attn, experts_w, out);
}

// Round 2
// 166.387 us; speedup vs baseline: 1.4581x; 1.4581x over previous
//
#include <hip/hip_runtime.h>
#include <math.h>

#define B_ 2
#define N_ 4100
#define C_ 768
#define T_ 4
#define H_ 12
#define D_ 64
#define M_ 4096
#define S_ 48          // T_*H_
#define KS_ 6          // k-split for score GEMM
#define KC_ 128        // channels per k-split chunk (2 sub-chunks of 64)
#define SCALE 0.125f   // d^-0.5 = 1/8

// ---- top-2 helpers (ties -> lowest index, matching jax.lax.top_k) ----
__device__ __forceinline__ bool better(float va, int ia, float vb, int ib) {
  return (va > vb) || (va == vb && ia < ib);
}

__device__ __forceinline__ void merge2(float& v1, int& i1, float& v2, int& i2,
                                       float ov1, int oi1, float ov2, int oi2) {
  if (better(ov1, oi1, v1, i1)) {
    float tv; int ti;
    tv = v1; ti = i1; v1 = ov1; i1 = oi1; ov1 = tv; oi1 = ti;
    tv = v2; ti = i2; v2 = ov2; i2 = oi2; ov2 = tv; oi2 = ti;
  }
  if (better(ov1, oi1, v2, i2)) { v2 = ov1; i2 = oi1; }
}

// ---- K1: q[b,t,o] = SCALE * x[b,t,:]·qs_w[t,o,:]   (block = (b,t,oc), 64 o per block)
__global__ __launch_bounds__(256) void q_kernel(const float* __restrict__ x,
    const float* __restrict__ qs_w, float* __restrict__ qbuf) {
  const int oc = blockIdx.x % 12;
  const int t = (blockIdx.x / 12) % T_;
  const int b = blockIdx.x / (12 * T_);
  const int tid = threadIdx.x;
  __shared__ float xs[C_];
  __shared__ float red[256];
  for (int i = tid; i < C_; i += 256) xs[i] = x[((size_t)b * N_ + t) * C_ + i];
  __syncthreads();
  const int j = tid & 63;
  const int pt = tid >> 6;      // 4 parts of 192 channels
  const int o = oc * 64 + j;
  const float* wr = qs_w + ((size_t)t * C_ + o) * C_ + pt * 192;
  float a = 0.f;
  for (int c = 0; c < 192; ++c) a += xs[pt * 192 + c] * wr[c];
  red[tid] = a;
  __syncthreads();
  if (tid < 64) {
    float v = (red[tid] + red[tid + 64] + red[tid + 128] + red[tid + 192]) * SCALE;
    qbuf[((size_t)b * T_ + t) * C_ + o] = v;
  }
}

// ---- K2: qk[b,s,c] = q[b,t,h-block]·kv_w[k-rows, c]   (block = (b,t,h))
__global__ __launch_bounds__(256) void qk_kernel(const float* __restrict__ qbuf,
    const float* __restrict__ kv_w, float* __restrict__ qk) {
  const int h = blockIdx.x % H_;
  const int t = (blockIdx.x / H_) % T_;
  const int b = blockIdx.x / (T_ * H_);
  const int tid = threadIdx.x;
  __shared__ float qs[D_];
  if (tid < 64) qs[tid] = qbuf[((size_t)b * T_ + t) * C_ + h * 64 + tid];
  __syncthreads();
  for (int c = tid; c < C_; c += 256) {
    float a = 0.f;
    #pragma unroll 8
    for (int j = 0; j < 64; ++j) a += qs[j] * kv_w[((size_t)(h * 64 + j)) * C_ + c];
    qk[(((size_t)b * T_ + t) * H_ + h) * C_ + c] = a;
  }
}

// ---- K3: partial scores, k-split. block = (b, mtile=64m, kc); writes part[kc][b][s][m]
__global__ __launch_bounds__(256) void score_kernel(const float* __restrict__ x,
    const float* __restrict__ qk, float* __restrict__ part) {
  const int mt = blockIdx.x & 63;
  const int b = blockIdx.x >> 6;
  const int kc = blockIdx.y;
  const int tid = threadIdx.x;
  const int m0 = mt * 64;

  __shared__ __align__(16) float fbuf[64][68];
  __shared__ __align__(16) float qkbuf[48][68];

  const int mg = tid & 15;   // m rows: mg + 16u
  const int sg = tid >> 4;   // s cols: sg*3 + i

  float acc[4][3];
  #pragma unroll
  for (int u = 0; u < 4; ++u)
    #pragma unroll
    for (int i = 0; i < 3; ++i) acc[u][i] = 0.f;

  const float* xb = x + ((size_t)b * N_ + T_ + m0) * C_ + kc * KC_;
  const float* qkb = qk + (size_t)b * S_ * C_ + kc * KC_;

  for (int cc = 0; cc < KC_ / 64; ++cc) {
    __syncthreads();
    for (int i = tid; i < 64 * 16; i += 256) {
      int row = i >> 4, c4 = i & 15;
      *(float4*)&fbuf[row][c4 * 4] =
          *(const float4*)(xb + (size_t)row * C_ + cc * 64 + c4 * 4);
    }
    for (int i = tid; i < 48 * 16; i += 256) {
      int s = i >> 4, c4 = i & 15;
      *(float4*)&qkbuf[s][c4 * 4] =
          *(const float4*)(qkb + (size_t)s * C_ + cc * 64 + c4 * 4);
    }
    __syncthreads();
    #pragma unroll 4
    for (int c4 = 0; c4 < 16; ++c4) {
      float4 f[4], q[3];
      f[0] = *(const float4*)&fbuf[mg][c4 * 4];
      f[1] = *(const float4*)&fbuf[mg + 16][c4 * 4];
      f[2] = *(const float4*)&fbuf[mg + 32][c4 * 4];
      f[3] = *(const float4*)&fbuf[mg + 48][c4 * 4];
      q[0] = *(const float4*)&qkbuf[sg * 3 + 0][c4 * 4];
      q[1] = *(const float4*)&qkbuf[sg * 3 + 1][c4 * 4];
      q[2] = *(const float4*)&qkbuf[sg * 3 + 2][c4 * 4];
      #pragma unroll
      for (int u = 0; u < 4; ++u)
        #pragma unroll
        for (int i = 0; i < 3; ++i)
          acc[u][i] += f[u].x * q[i].x + f[u].y * q[i].y +
                       f[u].z * q[i].z + f[u].w * q[i].w;
    }
  }

  #pragma unroll
  for (int i = 0; i < 3; ++i) {
    int s = sg * 3 + i;
    float* pp = part + (((size_t)kc * B_ + b) * S_ + s) * M_ + m0 + mg;
    #pragma unroll
    for (int u = 0; u < 4; ++u) pp[16 * u] = acc[u][i];
  }
}

// ---- K4: sum k-split partials, global top-2 + softmax weights. block = (b,s)
__global__ __launch_bounds__(256) void top2_kernel(const float* __restrict__ part,
                                                   float* __restrict__ top2) {
  const int s = blockIdx.x % S_;
  const int b = blockIdx.x / S_;
  const int tid = threadIdx.x;
  float v1 = -INFINITY, v2 = -INFINITY;
  int i1 = 0x7fffffff, i2 = 0x7fffffff;
  const float* p0 = part + ((size_t)b * S_ + s) * M_;
  const size_t kstride = (size_t)B_ * S_ * M_;
  for (int m = tid; m < M_; m += 256) {
    float v = 0.f;
    #pragma unroll
    for (int kc = 0; kc < KS_; ++kc) v += p0[kc * kstride + m];
    if (better(v, m, v1, i1)) { v2 = v1; i2 = i1; v1 = v; i1 = m; }
    else if (better(v, m, v2, i2)) { v2 = v; i2 = m; }
  }
  #pragma unroll
  for (int off = 1; off < 64; off <<= 1) {
    float ov1 = __shfl_xor(v1, off);
    int   oi1 = __shfl_xor(i1, off);
    float ov2 = __shfl_xor(v2, off);
    int   oi2 = __shfl_xor(i2, off);
    merge2(v1, i1, v2, i2, ov1, oi1, ov2, oi2);
  }
  __shared__ float cbuf[4][4];
  const int w = tid >> 6, lane = tid & 63;
  if (lane == 0) {
    cbuf[w][0] = v1; ((int*)cbuf[w])[1] = i1;
    cbuf[w][2] = v2; ((int*)cbuf[w])[3] = i2;
  }
  __syncthreads();
  if (tid == 0) {
    for (int ww = 1; ww < 4; ++ww)
      merge2(v1, i1, v2, i2, cbuf[ww][0], ((int*)cbuf[ww])[1],
             cbuf[ww][2], ((int*)cbuf[ww])[3]);
    float w1 = 1.f / (1.f + expf(v2 - v1));
    float* tp = top2 + ((size_t)b * S_ + s) * 4;
    ((int*)tp)[0] = i1; ((int*)tp)[1] = i2;
    tp[2] = w1; tp[3] = 1.f - w1;
  }
}

// ---- K5: fused v-projection (attn_token piece) + sparse expert scatter. block = (b,t,h)
__global__ __launch_bounds__(256) void gather_kernel(const float* __restrict__ x,
    const float* __restrict__ kv_w, const float* __restrict__ experts_w,
    const float* __restrict__ top2, float* __restrict__ attn, float* __restrict__ out) {
  const int h = blockIdx.x % H_;
  const int t = (blockIdx.x / H_) % T_;
  const int b = blockIdx.x / S_;
  const int tid = threadIdx.x;
  const float* tp = top2 + (size_t)blockIdx.x * 4;
  const int i1 = ((const int*)tp)[0];
  const int i2 = ((const int*)tp)[1];
  const float w1 = tp[2], w2 = tp[3];
  __shared__ float f0[C_], f1[C_], fc[C_], red[256];
  const float* r0 = x + ((size_t)b * N_ + T_ + i1) * C_;
  const float* r1 = x + ((size_t)b * N_ + T_ + i2) * C_;
  for (int i = tid; i < C_; i += 256) {
    float a = r0[i], bb = r1[i];
    f0[i] = a; f1[i] = bb; fc[i] = w1 * a + w2 * bb;
  }
  __syncthreads();
  // v-projection on the combined row: attn[b,t,h*64+j] = kv_w[V row]·fc
  const int j = tid & 63, pt = tid >> 6;
  {
    const float* kr = kv_w + ((size_t)(C_ + h * 64 + j)) * C_ + pt * 192;
    float a = 0.f;
    for (int c = 0; c < 192; ++c) a += fc[pt * 192 + c] * kr[c];
    red[tid] = a;
  }
  __syncthreads();
  if (tid < 64)
    attn[((size_t)b * T_ + t) * C_ + h * 64 + tid] =
        red[tid] + red[tid + 64] + red[tid + 128] + red[tid + 192];
  // sparse feature_output: out[row_k, o] += w_k * experts_w[t][o][h-block]·f_k[h-block]
  const size_t o0 = ((size_t)b * N_ + T_ + i1) * C_;
  const size_t o1 = ((size_t)b * N_ + T_ + i2) * C_;
  for (int o = tid; o < C_; o += 256) {
    const float* er = experts_w + ((size_t)t * C_ + o) * C_ + h * 64;
    float a0 = 0.f, a1 = 0.f;
    #pragma unroll 8
    for (int c = 0; c < 64; ++c) {
      float e = er[c];
      a0 += e * f0[h * 64 + c];
      a1 += e * f1[h * 64 + c];
    }
    atomicAdd(&out[o0 + o], w1 * a0);
    atomicAdd(&out[o1 + o], w2 * a1);
  }
}

// ---- K6: token_output[b,t,o] = attn_token[b,t,:]·experts_w[t,o,:]  (block = (b,t,oc))
__global__ __launch_bounds__(256) void token_kernel(const float* __restrict__ attn,
    const float* __restrict__ experts_w, float* __restrict__ out) {
  const int oc = blockIdx.x % 12;
  const int t = (blockIdx.x / 12) % T_;
  const int b = blockIdx.x / (12 * T_);
  const int tid = threadIdx.x;
  __shared__ float ar[C_];
  __shared__ float red[256];
  for (int i = tid; i < C_; i += 256) ar[i] = attn[((size_t)b * T_ + t) * C_ + i];
  __syncthreads();
  const int j = tid & 63, pt = tid >> 6;
  const int o = oc * 64 + j;
  const float* er = experts_w + ((size_t)t * C_ + o) * C_ + pt * 192;
  float a = 0.f;
  for (int c = 0; c < 192; ++c) a += ar[pt * 192 + c] * er[c];
  red[tid] = a;
  __syncthreads();
  if (tid < 64)
    out[((size_t)b * N_ + t) * C_ + oc * 64 + tid] =
        red[tid] + red[tid + 64] + red[tid + 128] + red[tid + 192];
}

extern "C" void kernel_launch(void* const* d_in, const int* in_sizes, int n_in,
                              void* d_out, int out_size, void* d_ws, size_t ws_size,
                              hipStream_t stream) {
  const float* x         = (const float*)d_in[0];
  const float* qs_w      = (const float*)d_in[1];
  const float* kv_w      = (const float*)d_in[2];
  const float* experts_w = (const float*)d_in[3];
  float* out = (float*)d_out;

  float* ws   = (float*)d_ws;
  float* qbuf = ws;                                    // B*T*C          = 6144
  float* qk   = qbuf + (size_t)B_ * T_ * C_;           // B*S*C          = 73728
  float* part = qk + (size_t)B_ * S_ * C_;             // KS*B*S*M       = 2359296
  float* top2 = part + (size_t)KS_ * B_ * S_ * M_;     // B*S*4          = 384
  float* attn = top2 + (size_t)B_ * S_ * 4;            // B*T*C          = 6144

  hipMemsetAsync(d_out, 0, (size_t)out_size * sizeof(float), stream);

  hipLaunchKernelGGL(q_kernel,     dim3(B_ * T_ * 12),      dim3(256), 0, stream, x, qs_w, qbuf);
  hipLaunchKernelGGL(qk_kernel,    dim3(B_ * T_ * H_),      dim3(256), 0, stream, qbuf, kv_w, qk);
  hipLaunchKernelGGL(score_kernel, dim3(B_ * 64, KS_),      dim3(256), 0, stream, x, qk, part);
  hipLaunchKernelGGL(top2_kernel,  dim3(B_ * S_),           dim3(256), 0, stream, part, top2);
  hipLaunchKernelGGL(gather_kernel,dim3(B_ * S_),           dim3(256), 0, stream, x, kv_w, experts_w, top2, attn, out);
  hipLaunchKernelGGL(token_kernel, dim3(B_ * T_ * 12),      dim3(256), 0, stream, attn, experts_w, out);
}

// Round 3
// 153.285 us; speedup vs baseline: 1.5827x; 1.0855x over previous
//
#include <hip/hip_runtime.h>
#include <math.h>

#define B_ 2
#define N_ 4100
#define C_ 768
#define T_ 4
#define H_ 12
#define D_ 64
#define M_ 4096
#define S_ 48          // T_*H_
#define KS_ 12         // k-split for score GEMM
#define KC_ 64         // channels per k-split chunk
#define SCALE 0.125f   // d^-0.5 = 1/8

// ---- top-2 helpers (ties -> lowest index, matching jax.lax.top_k) ----
__device__ __forceinline__ bool better(float va, int ia, float vb, int ib) {
  return (va > vb) || (va == vb && ia < ib);
}

__device__ __forceinline__ void merge2(float& v1, int& i1, float& v2, int& i2,
                                       float ov1, int oi1, float ov2, int oi2) {
  if (better(ov1, oi1, v1, i1)) {
    float tv; int ti;
    tv = v1; ti = i1; v1 = ov1; i1 = oi1; ov1 = tv; oi1 = ti;
    tv = v2; ti = i2; v2 = ov2; i2 = oi2; ov2 = tv; oi2 = ti;
  }
  if (better(ov1, oi1, v2, i2)) { v2 = ov1; i2 = oi1; }
}

// ---- K1: fused q + qk.  block = (b,t,h).
// qseg[j] = SCALE * x[b,t,:]·qs_w[t, h*64+j, :]
// qk[b,s,c] = qseg·kv_w[h*64.. , c]
__global__ __launch_bounds__(256) void qk_kernel(const float* __restrict__ x,
    const float* __restrict__ qs_w, const float* __restrict__ kv_w,
    float* __restrict__ qk) {
  const int h = blockIdx.x % H_;
  const int t = (blockIdx.x / H_) % T_;
  const int b = blockIdx.x / S_;
  const int tid = threadIdx.x;
  __shared__ float xs[C_];
  __shared__ float red[256];
  __shared__ float qseg[D_];
  for (int i = tid; i < C_; i += 256) xs[i] = x[((size_t)b * N_ + t) * C_ + i];
  __syncthreads();
  {
    const int j = tid & 63;
    const int pt = tid >> 6;          // 4 parts of 192 channels
    const float* wr = qs_w + ((size_t)t * C_ + h * D_ + j) * C_ + pt * 192;
    float a = 0.f;
    for (int c = 0; c < 192; ++c) a += xs[pt * 192 + c] * wr[c];
    red[tid] = a;
  }
  __syncthreads();
  if (tid < 64)
    qseg[tid] = (red[tid] + red[tid + 64] + red[tid + 128] + red[tid + 192]) * SCALE;
  __syncthreads();
  for (int c = tid; c < C_; c += 256) {
    float a = 0.f;
    #pragma unroll 8
    for (int j = 0; j < 64; ++j) a += qseg[j] * kv_w[((size_t)(h * D_ + j)) * C_ + c];
    qk[((size_t)blockIdx.x) * C_ + c] = a;
  }
}

// ---- K2: partial scores, k-split. block = (b, mtile of 64 m) x (kc of 64 c)
__global__ __launch_bounds__(256) void score_kernel(const float* __restrict__ x,
    const float* __restrict__ qk, float* __restrict__ part) {
  const int mt = blockIdx.x & 63;
  const int b = blockIdx.x >> 6;
  const int kc = blockIdx.y;
  const int tid = threadIdx.x;
  const int m0 = mt * 64;

  __shared__ __align__(16) float fbuf[64][68];
  __shared__ __align__(16) float qkbuf[48][68];

  const float* xb = x + ((size_t)b * N_ + T_ + m0) * C_ + kc * KC_;
  const float* qkb = qk + (size_t)b * S_ * C_ + kc * KC_;

  for (int i = tid; i < 64 * 16; i += 256) {
    int row = i >> 4, c4 = i & 15;
    *(float4*)&fbuf[row][c4 * 4] =
        *(const float4*)(xb + (size_t)row * C_ + c4 * 4);
  }
  for (int i = tid; i < 48 * 16; i += 256) {
    int s = i >> 4, c4 = i & 15;
    *(float4*)&qkbuf[s][c4 * 4] =
        *(const float4*)(qkb + (size_t)s * C_ + c4 * 4);
  }
  __syncthreads();

  const int mg = tid & 15;   // m rows: mg + 16u
  const int sg = tid >> 4;   // s cols: sg*3 + i

  float acc[4][3];
  #pragma unroll
  for (int u = 0; u < 4; ++u)
    #pragma unroll
    for (int i = 0; i < 3; ++i) acc[u][i] = 0.f;

  #pragma unroll 4
  for (int c4 = 0; c4 < 16; ++c4) {
    float4 f[4], q[3];
    f[0] = *(const float4*)&fbuf[mg][c4 * 4];
    f[1] = *(const float4*)&fbuf[mg + 16][c4 * 4];
    f[2] = *(const float4*)&fbuf[mg + 32][c4 * 4];
    f[3] = *(const float4*)&fbuf[mg + 48][c4 * 4];
    q[0] = *(const float4*)&qkbuf[sg * 3 + 0][c4 * 4];
    q[1] = *(const float4*)&qkbuf[sg * 3 + 1][c4 * 4];
    q[2] = *(const float4*)&qkbuf[sg * 3 + 2][c4 * 4];
    #pragma unroll
    for (int u = 0; u < 4; ++u)
      #pragma unroll
      for (int i = 0; i < 3; ++i)
        acc[u][i] += f[u].x * q[i].x + f[u].y * q[i].y +
                     f[u].z * q[i].z + f[u].w * q[i].w;
  }

  #pragma unroll
  for (int i = 0; i < 3; ++i) {
    int s = sg * 3 + i;
    float* pp = part + (((size_t)kc * B_ + b) * S_ + s) * M_ + m0 + mg;
    #pragma unroll
    for (int u = 0; u < 4; ++u) pp[16 * u] = acc[u][i];
  }
}

// ---- K3: fused top-2 merge + v-projection + token scatter + feature scatter.
// block = (b,s), s = t*H_+h.
__global__ __launch_bounds__(256) void gather_kernel(const float* __restrict__ x,
    const float* __restrict__ kv_w, const float* __restrict__ experts_w,
    const float* __restrict__ part, float* __restrict__ out) {
  const int h = blockIdx.x % H_;
  const int t = (blockIdx.x / H_) % T_;
  const int b = blockIdx.x / S_;
  const int tid = threadIdx.x;

  __shared__ float f0[C_], f1[C_], fc[C_], red[256];
  __shared__ float attnh[D_];
  __shared__ float cbuf[4][4];
  __shared__ float sel[4];

  // --- stage 1: sum k-split partials, top-2 + softmax weights ---
  {
    float v1 = -INFINITY, v2 = -INFINITY;
    int i1 = 0x7fffffff, i2 = 0x7fffffff;
    const float* p0 = part + ((size_t)b * S_ + (t * H_ + h)) * M_;
    const size_t kstride = (size_t)B_ * S_ * M_;
    for (int m = tid; m < M_; m += 256) {
      float v = 0.f;
      #pragma unroll
      for (int kc = 0; kc < KS_; ++kc) v += p0[kc * kstride + m];
      if (better(v, m, v1, i1)) { v2 = v1; i2 = i1; v1 = v; i1 = m; }
      else if (better(v, m, v2, i2)) { v2 = v; i2 = m; }
    }
    #pragma unroll
    for (int off = 1; off < 64; off <<= 1) {
      float ov1 = __shfl_xor(v1, off);
      int   oi1 = __shfl_xor(i1, off);
      float ov2 = __shfl_xor(v2, off);
      int   oi2 = __shfl_xor(i2, off);
      merge2(v1, i1, v2, i2, ov1, oi1, ov2, oi2);
    }
    const int w = tid >> 6, lane = tid & 63;
    if (lane == 0) {
      cbuf[w][0] = v1; ((int*)cbuf[w])[1] = i1;
      cbuf[w][2] = v2; ((int*)cbuf[w])[3] = i2;
    }
    __syncthreads();
    if (tid == 0) {
      for (int ww = 1; ww < 4; ++ww)
        merge2(v1, i1, v2, i2, cbuf[ww][0], ((int*)cbuf[ww])[1],
               cbuf[ww][2], ((int*)cbuf[ww])[3]);
      float w1 = 1.f / (1.f + expf(v2 - v1));
      ((int*)sel)[0] = i1; ((int*)sel)[1] = i2;
      sel[2] = w1; sel[3] = 1.f - w1;
    }
    __syncthreads();
  }
  const int i1 = ((const int*)sel)[0];
  const int i2 = ((const int*)sel)[1];
  const float w1 = sel[2], w2 = sel[3];

  // --- stage 2: load selected feature rows ---
  const float* r0 = x + ((size_t)b * N_ + T_ + i1) * C_;
  const float* r1 = x + ((size_t)b * N_ + T_ + i2) * C_;
  for (int i = tid; i < C_; i += 256) {
    float a = r0[i], bb = r1[i];
    f0[i] = a; f1[i] = bb; fc[i] = w1 * a + w2 * bb;
  }
  __syncthreads();

  // --- stage 3: v-projection on combined row -> attnh[64] ---
  const int j = tid & 63, pt = tid >> 6;
  {
    const float* kr = kv_w + ((size_t)(C_ + h * D_ + j)) * C_ + pt * 192;
    float a = 0.f;
    for (int c = 0; c < 192; ++c) a += fc[pt * 192 + c] * kr[c];
    red[tid] = a;
  }
  __syncthreads();
  if (tid < 64)
    attnh[tid] = red[tid] + red[tid + 64] + red[tid + 128] + red[tid + 192];
  __syncthreads();

  // --- stage 4: token + feature scatter (shared experts_w slice) ---
  const size_t ot = ((size_t)b * N_ + t) * C_;
  const size_t o0 = ((size_t)b * N_ + T_ + i1) * C_;
  const size_t o1 = ((size_t)b * N_ + T_ + i2) * C_;
  for (int o = tid; o < C_; o += 256) {
    const float* er = experts_w + ((size_t)t * C_ + o) * C_ + h * D_;
    float at = 0.f, a0 = 0.f, a1 = 0.f;
    #pragma unroll 8
    for (int c = 0; c < D_; ++c) {
      float e = er[c];
      at += e * attnh[c];
      a0 += e * f0[h * D_ + c];
      a1 += e * f1[h * D_ + c];
    }
    atomicAdd(&out[ot + o], at);
    atomicAdd(&out[o0 + o], w1 * a0);
    atomicAdd(&out[o1 + o], w2 * a1);
  }
}

extern "C" void kernel_launch(void* const* d_in, const int* in_sizes, int n_in,
                              void* d_out, int out_size, void* d_ws, size_t ws_size,
                              hipStream_t stream) {
  const float* x         = (const float*)d_in[0];
  const float* qs_w      = (const float*)d_in[1];
  const float* kv_w      = (const float*)d_in[2];
  const float* experts_w = (const float*)d_in[3];
  float* out = (float*)d_out;

  float* ws   = (float*)d_ws;
  float* qk   = ws;                                  // B*S*C     = 73728 floats
  float* part = qk + (size_t)B_ * S_ * C_;           // KS*B*S*M  = 4718592 floats

  hipMemsetAsync(d_out, 0, (size_t)out_size * sizeof(float), stream);

  hipLaunchKernelGGL(qk_kernel,    dim3(B_ * S_),      dim3(256), 0, stream, x, qs_w, kv_w, qk);
  hipLaunchKernelGGL(score_kernel, dim3(B_ * 64, KS_), dim3(256), 0, stream, x, qk, part);
  hipLaunchKernelGGL(gather_kernel,dim3(B_ * S_),      dim3(256), 0, stream, x, kv_w, experts_w, part, out);
}

// Round 4
// 149.692 us; speedup vs baseline: 1.6207x; 1.0240x over previous
//
#include <hip/hip_runtime.h>
#include <math.h>

#define B_ 2
#define N_ 4100
#define C_ 768
#define T_ 4
#define H_ 12
#define D_ 64
#define M_ 4096
#define S_ 48          // T_*H_
#define KS_ 12         // k-split for score GEMM
#define KC_ 64         // channels per k-split chunk
#define SEG_ 8         // m-segments per (b,s) in reduce
#define SCALE 0.125f   // d^-0.5 = 1/8

// ---- top-2 helpers (ties -> lowest index, matching jax.lax.top_k) ----
__device__ __forceinline__ bool better(float va, int ia, float vb, int ib) {
  return (va > vb) || (va == vb && ia < ib);
}

__device__ __forceinline__ void merge2(float& v1, int& i1, float& v2, int& i2,
                                       float ov1, int oi1, float ov2, int oi2) {
  if (better(ov1, oi1, v1, i1)) {
    float tv; int ti;
    tv = v1; ti = i1; v1 = ov1; i1 = oi1; ov1 = tv; oi1 = ti;
    tv = v2; ti = i2; v2 = ov2; i2 = oi2; ov2 = tv; oi2 = ti;
  }
  if (better(ov1, oi1, v2, i2)) { v2 = ov1; i2 = oi1; }
}

// ---- K1: fused q + qk.  block = (b,t,h).  h==0 blocks also zero token-out rows.
__global__ __launch_bounds__(256) void qk_kernel(const float* __restrict__ x,
    const float* __restrict__ qs_w, const float* __restrict__ kv_w,
    float* __restrict__ qk, float* __restrict__ out) {
  const int h = blockIdx.x % H_;
  const int t = (blockIdx.x / H_) % T_;
  const int b = blockIdx.x / S_;
  const int tid = threadIdx.x;
  __shared__ float xs[C_];
  __shared__ float red[256];
  __shared__ float qseg[D_];
  if (h == 0)   // zero token_output row (b,t) — gather atomically adds later
    for (int i = tid; i < C_; i += 256) out[((size_t)b * N_ + t) * C_ + i] = 0.f;
  for (int i = tid; i < C_; i += 256) xs[i] = x[((size_t)b * N_ + t) * C_ + i];
  __syncthreads();
  {
    const int j = tid & 63;
    const int pt = tid >> 6;          // 4 parts of 192 channels
    const float* wr = qs_w + ((size_t)t * C_ + h * D_ + j) * C_ + pt * 192;
    float a = 0.f;
    for (int c = 0; c < 192; ++c) a += xs[pt * 192 + c] * wr[c];
    red[tid] = a;
  }
  __syncthreads();
  if (tid < 64)
    qseg[tid] = (red[tid] + red[tid + 64] + red[tid + 128] + red[tid + 192]) * SCALE;
  __syncthreads();
  for (int c = tid; c < C_; c += 256) {
    float a = 0.f;
    #pragma unroll 8
    for (int j = 0; j < 64; ++j) a += qseg[j] * kv_w[((size_t)(h * D_ + j)) * C_ + c];
    qk[((size_t)blockIdx.x) * C_ + c] = a;
  }
}

// ---- K2: partial scores, k-split. block = (b, mtile of 64 m) x (kc of 64 c).
// kc==0 blocks also zero their 64 feature-out rows.
__global__ __launch_bounds__(256) void score_kernel(const float* __restrict__ x,
    const float* __restrict__ qk, float* __restrict__ part, float* __restrict__ out) {
  const int mt = blockIdx.x & 63;
  const int b = blockIdx.x >> 6;
  const int kc = blockIdx.y;
  const int tid = threadIdx.x;
  const int m0 = mt * 64;

  __shared__ __align__(16) float fbuf[64][68];
  __shared__ __align__(16) float qkbuf[48][68];

  if (kc == 0) {   // zero feature_output rows (b, T_+m0 .. +63)
    float4 z = make_float4(0.f, 0.f, 0.f, 0.f);
    float4* outv = (float4*)(out + ((size_t)b * N_ + T_ + m0) * C_);
    for (int i = tid; i < 64 * C_ / 4; i += 256) outv[i] = z;
  }

  const float* xb = x + ((size_t)b * N_ + T_ + m0) * C_ + kc * KC_;
  const float* qkb = qk + (size_t)b * S_ * C_ + kc * KC_;

  for (int i = tid; i < 64 * 16; i += 256) {
    int row = i >> 4, c4 = i & 15;
    *(float4*)&fbuf[row][c4 * 4] =
        *(const float4*)(xb + (size_t)row * C_ + c4 * 4);
  }
  for (int i = tid; i < 48 * 16; i += 256) {
    int s = i >> 4, c4 = i & 15;
    *(float4*)&qkbuf[s][c4 * 4] =
        *(const float4*)(qkb + (size_t)s * C_ + c4 * 4);
  }
  __syncthreads();

  const int mg = tid & 15;   // m rows: mg + 16u
  const int sg = tid >> 4;   // s cols: sg*3 + i

  float acc[4][3];
  #pragma unroll
  for (int u = 0; u < 4; ++u)
    #pragma unroll
    for (int i = 0; i < 3; ++i) acc[u][i] = 0.f;

  #pragma unroll 4
  for (int c4 = 0; c4 < 16; ++c4) {
    float4 f[4], q[3];
    f[0] = *(const float4*)&fbuf[mg][c4 * 4];
    f[1] = *(const float4*)&fbuf[mg + 16][c4 * 4];
    f[2] = *(const float4*)&fbuf[mg + 32][c4 * 4];
    f[3] = *(const float4*)&fbuf[mg + 48][c4 * 4];
    q[0] = *(const float4*)&qkbuf[sg * 3 + 0][c4 * 4];
    q[1] = *(const float4*)&qkbuf[sg * 3 + 1][c4 * 4];
    q[2] = *(const float4*)&qkbuf[sg * 3 + 2][c4 * 4];
    #pragma unroll
    for (int u = 0; u < 4; ++u)
      #pragma unroll
      for (int i = 0; i < 3; ++i)
        acc[u][i] += f[u].x * q[i].x + f[u].y * q[i].y +
                     f[u].z * q[i].z + f[u].w * q[i].w;
  }

  #pragma unroll
  for (int i = 0; i < 3; ++i) {
    int s = sg * 3 + i;
    float* pp = part + (((size_t)kc * B_ + b) * S_ + s) * M_ + m0 + mg;
    #pragma unroll
    for (int u = 0; u < 4; ++u) pp[16 * u] = acc[u][i];
  }
}

// ---- K3: sum k-split partials over a 512-m segment + segment top-2 candidate.
// block = (b*S+s)*8 + seg; 256 threads, 2 m each.
__global__ __launch_bounds__(256) void reduce_kernel(const float* __restrict__ part,
                                                     float* __restrict__ cand) {
  const int seg = blockIdx.x & 7;
  const int bs = blockIdx.x >> 3;     // b*S + s
  const int tid = threadIdx.x;
  const size_t kstride = (size_t)B_ * S_ * M_;
  const float* p0 = part + (size_t)bs * M_ + seg * 512 + tid * 2;
  float a0 = 0.f, a1 = 0.f;
  #pragma unroll
  for (int kc = 0; kc < KS_; ++kc) {
    float2 v = *(const float2*)(p0 + kc * kstride);
    a0 += v.x; a1 += v.y;
  }
  const int mA = seg * 512 + tid * 2;
  float v1, v2; int i1, i2;
  if (better(a0, mA, a1, mA + 1)) { v1 = a0; i1 = mA; v2 = a1; i2 = mA + 1; }
  else                            { v1 = a1; i1 = mA + 1; v2 = a0; i2 = mA; }
  #pragma unroll
  for (int off = 1; off < 64; off <<= 1) {
    float ov1 = __shfl_xor(v1, off);
    int   oi1 = __shfl_xor(i1, off);
    float ov2 = __shfl_xor(v2, off);
    int   oi2 = __shfl_xor(i2, off);
    merge2(v1, i1, v2, i2, ov1, oi1, ov2, oi2);
  }
  __shared__ float cbuf[4][4];
  const int w = tid >> 6, lane = tid & 63;
  if (lane == 0) {
    cbuf[w][0] = v1; ((int*)cbuf[w])[1] = i1;
    cbuf[w][2] = v2; ((int*)cbuf[w])[3] = i2;
  }
  __syncthreads();
  if (tid == 0) {
    for (int ww = 1; ww < 4; ++ww)
      merge2(v1, i1, v2, i2, cbuf[ww][0], ((int*)cbuf[ww])[1],
             cbuf[ww][2], ((int*)cbuf[ww])[3]);
    ((float4*)cand)[blockIdx.x] =
        make_float4(v1, __int_as_float(i1), v2, __int_as_float(i2));
  }
}

// ---- K4: merge 8 candidates -> top-2 + softmax; v-projection; token+feature scatter.
// block = (b,s), s = t*H_+h.
__global__ __launch_bounds__(256) void gather_kernel(const float* __restrict__ x,
    const float* __restrict__ kv_w, const float* __restrict__ experts_w,
    const float* __restrict__ cand, float* __restrict__ out) {
  const int h = blockIdx.x % H_;
  const int t = (blockIdx.x / H_) % T_;
  const int b = blockIdx.x / S_;
  const int tid = threadIdx.x;

  __shared__ float f0[C_], f1[C_], fc[C_], red[256];
  __shared__ float attnh[D_];
  __shared__ float sel[4];

  // --- stage 1: merge the 8 segment candidates ---
  if (tid < 8) {
    float4 cv = ((const float4*)cand)[blockIdx.x * 8 + tid];
    float v1 = cv.x, v2 = cv.z;
    int i1 = __float_as_int(cv.y), i2 = __float_as_int(cv.w);
    #pragma unroll
    for (int off = 1; off < 8; off <<= 1) {
      float ov1 = __shfl_xor(v1, off);
      int   oi1 = __shfl_xor(i1, off);
      float ov2 = __shfl_xor(v2, off);
      int   oi2 = __shfl_xor(i2, off);
      merge2(v1, i1, v2, i2, ov1, oi1, ov2, oi2);
    }
    if (tid == 0) {
      float w1 = 1.f / (1.f + expf(v2 - v1));
      ((int*)sel)[0] = i1; ((int*)sel)[1] = i2;
      sel[2] = w1; sel[3] = 1.f - w1;
    }
  }
  __syncthreads();
  const int i1 = ((const int*)sel)[0];
  const int i2 = ((const int*)sel)[1];
  const float w1 = sel[2], w2 = sel[3];

  // --- stage 2: load selected feature rows ---
  const float* r0 = x + ((size_t)b * N_ + T_ + i1) * C_;
  const float* r1 = x + ((size_t)b * N_ + T_ + i2) * C_;
  for (int i = tid; i < C_; i += 256) {
    float a = r0[i], bb = r1[i];
    f0[i] = a; f1[i] = bb; fc[i] = w1 * a + w2 * bb;
  }
  __syncthreads();

  // --- stage 3: v-projection on combined row -> attnh[64] ---
  const int j = tid & 63, pt = tid >> 6;
  {
    const float* kr = kv_w + ((size_t)(C_ + h * D_ + j)) * C_ + pt * 192;
    float a = 0.f;
    for (int c = 0; c < 192; ++c) a += fc[pt * 192 + c] * kr[c];
    red[tid] = a;
  }
  __syncthreads();
  if (tid < 64)
    attnh[tid] = red[tid] + red[tid + 64] + red[tid + 128] + red[tid + 192];
  __syncthreads();

  // --- stage 4: token + feature scatter (shared experts_w slice) ---
  const size_t ot = ((size_t)b * N_ + t) * C_;
  const size_t o0 = ((size_t)b * N_ + T_ + i1) * C_;
  const size_t o1 = ((size_t)b * N_ + T_ + i2) * C_;
  for (int o = tid; o < C_; o += 256) {
    const float* er = experts_w + ((size_t)t * C_ + o) * C_ + h * D_;
    float at = 0.f, a0 = 0.f, a1 = 0.f;
    #pragma unroll 8
    for (int c = 0; c < D_; ++c) {
      float e = er[c];
      at += e * attnh[c];
      a0 += e * f0[h * D_ + c];
      a1 += e * f1[h * D_ + c];
    }
    atomicAdd(&out[ot + o], at);
    atomicAdd(&out[o0 + o], w1 * a0);
    atomicAdd(&out[o1 + o], w2 * a1);
  }
}

extern "C" void kernel_launch(void* const* d_in, const int* in_sizes, int n_in,
                              void* d_out, int out_size, void* d_ws, size_t ws_size,
                              hipStream_t stream) {
  const float* x         = (const float*)d_in[0];
  const float* qs_w      = (const float*)d_in[1];
  const float* kv_w      = (const float*)d_in[2];
  const float* experts_w = (const float*)d_in[3];
  float* out = (float*)d_out;

  float* ws   = (float*)d_ws;
  float* qk   = ws;                                  // B*S*C       = 73728 floats
  float* part = qk + (size_t)B_ * S_ * C_;           // KS*B*S*M    = 4718592
  float* cand = part + (size_t)KS_ * B_ * S_ * M_;   // B*S*SEG*4   = 3072

  hipLaunchKernelGGL(qk_kernel,     dim3(B_ * S_),        dim3(256), 0, stream, x, qs_w, kv_w, qk, out);
  hipLaunchKernelGGL(score_kernel,  dim3(B_ * 64, KS_),   dim3(256), 0, stream, x, qk, part, out);
  hipLaunchKernelGGL(reduce_kernel, dim3(B_ * S_ * SEG_), dim3(256), 0, stream, part, cand);
  hipLaunchKernelGGL(gather_kernel, dim3(B_ * S_),        dim3(256), 0, stream, x, kv_w, experts_w, cand, out);
}